// Round 10
// baseline (58.247 us; speedup 1.0000x reference)
//
#include <hip/hip_runtime.h>

#define GDIM 104
#define GG (GDIM * GDIM)          // 10816
#define NA 3
#define NB 128
#define NCPT 2                    // cells per thread
#define NBLK 2704                 // NB*GG / (256*NCPT)
#define IMGF 832.0f
#define EPSF 1e-9f
#define PI_F 3.14159265358979323846f
#define INV_G (1.0f / 104.0f)

typedef float f32x4 __attribute__((ext_vector_type(4)));

// 1-instruction reciprocal (v_rcp_f32, rel err ~2^-22 — fine at threshold 348)
__device__ __forceinline__ float rcp_(float x) { return __builtin_amdgcn_rcpf(x); }

__device__ __forceinline__ float sigmoid_fast(float z) {
    return rcp_(1.0f + __expf(-z));
}

// acos minimax (Abramowitz-Stegun 4.4.45), |err| < 7e-5 rad
__device__ __forceinline__ float acos_fast(float x) {
    float ax = fabsf(x);
    float t = sqrtf(fmaxf(1.0f - ax, 0.0f));
    float p = fmaf(-0.0187293f, ax, 0.0742610f);
    p = fmaf(p, ax, -0.2121144f);
    p = fmaf(p, ax, 1.5707288f);
    float r = t * p;
    return (x < 0.0f) ? (PI_F - r) : r;
}

// Device-coherent write-through store / bypass load (cross-XCD L2s are NOT
// coherent; partials must round-trip the coherent point).
__device__ __forceinline__ void store_wt(float* p, float v) {
    asm volatile("global_store_dword %0, %1, off sc0 sc1" :: "v"(p), "v"(v) : "memory");
}
__device__ __forceinline__ float load_sc(const float* p) {
    float r;
    asm volatile("global_load_dword %0, %1, off sc0 sc1\n\ts_waitcnt vmcnt(0)"
                 : "=v"(r) : "v"(p) : "memory");
    return r;
}

// 2 cells/thread, lane-contiguous loads AND stores (R6 structure) + fused
// last-block finalize (split-k idiom) to drop the second kernel launch.
__global__ __launch_bounds__(256) void det_main(const float* __restrict__ x,
                                                const float* __restrict__ tg,
                                                f32x4* __restrict__ out4,
                                                float* __restrict__ ws,
                                                float* __restrict__ out_scalar) {
    const float PR[NA] = {20.0f / 8.0f, 50.0f / 8.0f, 110.0f / 8.0f};   // ANCHORS/stride
    const float AR[NA] = {20.0f / IMGF, 50.0f / IMGF, 110.0f / IMGF};   // ANCHORS/IMAGE_SIZE

    int tid  = threadIdx.x;
    int base = blockIdx.x * (256 * NCPT) + tid;

    // ---- issue loads up front (lane-contiguous scalar loads) ----
    int bb[NCPT], rr[NCPT];
    float vt[NCPT][4];     // targets [c][plane]
    float vp[NCPT][12];    // x       [c][plane]
#pragma unroll
    for (int c = 0; c < NCPT; ++c) {
        int gc = base + c * 256;
        int b = gc / GG;
        int r = gc - b * GG;
        bb[c] = b; rr[c] = r;
        const float* tb = tg + (size_t)b * (4 * GG) + r;
#pragma unroll
        for (int p = 0; p < 4; ++p) vt[c][p] = tb[(size_t)p * GG];
        const float* xb = x + (size_t)b * (12 * GG) + r;
#pragma unroll
        for (int p = 0; p < 12; ++p) vp[c][p] = xb[(size_t)p * GG];
    }

    float l_fl = 0.0f, l_di = 0.0f;
    int   l_n  = 0;

#pragma unroll
    for (int c = 0; c < NCPT; ++c) {
        int b = bb[c], r = rr[c];
        int i = r / GDIM;
        int j = r - i * GDIM;
        float fi = (float)i, fj = (float)j;

        float tx  = vt[c][0];
        float ty  = vt[c][1];
        float trr = vt[c][2];
        float cf  = vt[c][3];
        float tgx = (fj + tx) * INV_G;
        float tgy = (fi + ty) * INV_G;

        // best anchor = argmax riou (first-max tie rule via strict >)
        int best = 0;
        float bestv = -1.0f;
#pragma unroll
        for (int a = 0; a < NA; ++a) {
            float q = fminf(trr, AR[a]) * rcp_(fmaxf(trr, AR[a]) + EPSF);
            float ri = q * q;
            if (ri > bestv) { bestv = ri; best = a; }
        }
        bool pos = (cf > 0.5f);

        size_t obase = (size_t)b * (NA * GG) + r;
        float sbx = 0.0f, sby = 0.0f, sbr = 0.0f;
#pragma unroll
        for (int a = 0; a < NA; ++a) {
            float p0 = vp[c][a * 4 + 0];
            float p1 = vp[c][a * 4 + 1];
            float p2 = vp[c][a * 4 + 2];
            float p3 = vp[c][a * 4 + 3];

            float sx = sigmoid_fast(p0);
            float sy = sigmoid_fast(p1);
            float br = PR[a] * __expf(p2) * INV_G;

            float e   = __expf(-p3);
            float pc  = rcp_(1.0f + e);
            float l1e = __logf(1.0f + e);     // = -log_sigmoid(p3)

            f32x4 o;
            o.x = (sx + fj) * 8.0f;
            o.y = (sy + fi) * 8.0f;
            o.z = br * IMGF;
            o.w = pc;
            __builtin_nontemporal_store(o, &out4[obase + (size_t)a * GG]);

            bool obj = pos && (a == best);
            float u = 1.0f - pc;
            l_fl += obj ? 0.25f * u * u * l1e : 0.75f * pc * pc * (p3 + l1e);

            if (a == best) { sbx = (sx + fj) * INV_G; sby = (sy + fi) * INV_G; sbr = br; }
        }

        if (pos) {
            l_n += 1;
            float dx = sbx - tgx, dy = sby - tgy;
            float d2 = dx * dx + dy * dy;
            float d  = sqrtf(d2 + EPSF);
            float r1 = sbr, r2 = trr;
            float rmin = fminf(r1, r2), rmax = fmaxf(r1, r2);
            float a1 = (d2 + r1 * r1 - r2 * r2) * rcp_(2.0f * d * r1 + EPSF);
            a1 = fminf(fmaxf(a1, -1.0f), 1.0f);
            float a2 = (d2 + r2 * r2 - r1 * r1) * rcp_(2.0f * d * r2 + EPSF);
            a2 = fminf(fmaxf(a2, -1.0f), 1.0f);
            float tt = (-d + r1 + r2) * (d + r1 - r2) * (d - r1 + r2) * (d + r1 + r2);
            tt = fmaxf(tt, 0.0f);
            float lens = r1 * r1 * acos_fast(a1) + r2 * r2 * acos_fast(a2) - 0.5f * sqrtf(tt);
            float inter = (d >= r1 + r2) ? 0.0f
                         : ((d <= rmax - rmin) ? PI_F * rmin * rmin : lens);
            float uni = PI_F * (r1 * r1 + r2 * r2) - inter;
            float iou = inter * rcp_(uni + EPSF);
            float s = d + r1 + r2;
            float pen = d2 * rcp_(s * s + EPSF);
            l_di += 1.0f - iou + pen;
        }
    }

    // wave64 reduce
    float l_nf = (float)l_n;
#pragma unroll
    for (int off = 32; off > 0; off >>= 1) {
        l_di += __shfl_down(l_di, off);
        l_fl += __shfl_down(l_fl, off);
        l_nf += __shfl_down(l_nf, off);
    }

    __shared__ float sdiou[4], sfl[4], snn[4];
    __shared__ int amlast;
    int wid  = tid >> 6;
    int lane = tid & 63;
    if (lane == 0) { sdiou[wid] = l_di; sfl[wid] = l_fl; snn[wid] = l_nf; }
    __syncthreads();
    if (tid == 0) {
        float ds = 0.0f, fs = 0.0f, ns = 0.0f;
#pragma unroll
        for (int w = 0; w < 4; ++w) { ds += sdiou[w]; fs += sfl[w]; ns += snn[w]; }
        // publish partials device-coherently, then bump the arrival counter
        store_wt(&ws[blockIdx.x], ds);
        store_wt(&ws[NBLK + blockIdx.x], fs);
        store_wt(&ws[2 * NBLK + blockIdx.x], ns);
        asm volatile("s_waitcnt vmcnt(0)" ::: "memory");
        unsigned old = atomicAdd((unsigned*)(ws + 3 * NBLK), 1u);
        amlast = (old == NBLK - 1) ? 1 : 0;
    }
    __syncthreads();
    if (!amlast) return;

    // ---- last arriving block finalizes (fixed reduction order: deterministic) ----
    float ds = 0.0f, fs = 0.0f, ns = 0.0f;
    for (int k = tid; k < NBLK; k += 256) {
        ds += load_sc(&ws[k]);
        fs += load_sc(&ws[NBLK + k]);
        ns += load_sc(&ws[2 * NBLK + k]);
    }
#pragma unroll
    for (int off = 32; off > 0; off >>= 1) {
        ds += __shfl_down(ds, off);
        fs += __shfl_down(fs, off);
        ns += __shfl_down(ns, off);
    }
    __syncthreads();   // reuse the shared arrays safely
    if (lane == 0) { sdiou[wid] = ds; sfl[wid] = fs; snn[wid] = ns; }
    __syncthreads();
    if (tid == 0) {
        float D = 0.0f, F = 0.0f, N = 0.0f;
#pragma unroll
        for (int w = 0; w < 4; ++w) { D += sdiou[w]; F += sfl[w]; N += snn[w]; }
        double n = (N < 1.0f) ? 1.0 : (double)N;
        out_scalar[0] = (float)((double)D / n + (double)F / (double)((size_t)NB * NA * GG));
    }
}

extern "C" void kernel_launch(void* const* d_in, const int* in_sizes, int n_in,
                              void* d_out, int out_size, void* d_ws, size_t ws_size,
                              hipStream_t stream) {
    const float* x  = (const float*)d_in[0];
    const float* tg = (const float*)d_in[1];
    float* out = (float*)d_out;
    float* ws  = (float*)d_ws;

    // zero the arrival counter (float index 3*NBLK) each launch — graph-safe
    hipMemsetAsync(ws + 3 * NBLK, 0, sizeof(unsigned), stream);

    det_main<<<NBLK, 256, 0, stream>>>(x, tg, (f32x4*)out, ws,
                                       out + (size_t)NB * NA * GG * 4);
}

// Round 11
// 54.268 us; speedup vs baseline: 1.0733x; 1.0733x over previous
//
#include <hip/hip_runtime.h>

#define GDIM 104
#define GG (GDIM * GDIM)          // 10816
#define NA 3
#define NB 128
#define NCPT 2                    // cells per thread
#define NBLK 2704                 // NB*GG / (256*NCPT)
#define NSLOT 2816                // 256*11 >= NBLK (pad zeroed per launch)
#define IMGF 832.0f
#define EPSF 1e-9f
#define PI_F 3.14159265358979323846f
#define INV_G (1.0f / 104.0f)

typedef float f32x4 __attribute__((ext_vector_type(4)));

// 1-instruction reciprocal (v_rcp_f32, rel err ~2^-22 — fine at threshold 348)
__device__ __forceinline__ float rcp_(float x) { return __builtin_amdgcn_rcpf(x); }

__device__ __forceinline__ float sigmoid_fast(float z) {
    return rcp_(1.0f + __expf(-z));
}

// acos minimax (Abramowitz-Stegun 4.4.45), |err| < 7e-5 rad
__device__ __forceinline__ float acos_fast(float x) {
    float ax = fabsf(x);
    float t = sqrtf(fmaxf(1.0f - ax, 0.0f));
    float p = fmaf(-0.0187293f, ax, 0.0742610f);
    p = fmaf(p, ax, -0.2121144f);
    p = fmaf(p, ax, 1.5707288f);
    float r = t * p;
    return (x < 0.0f) ? (PI_F - r) : r;
}

// 2 cells/thread, lane-contiguous loads AND stores (R6 structure) + fused
// last-block finalize with BATCHED coherent reads (R10's serialized tail fixed).
__global__ __launch_bounds__(256) void det_main(const float* __restrict__ x,
                                                const float* __restrict__ tg,
                                                f32x4* __restrict__ out4,
                                                f32x4* __restrict__ ws4,
                                                unsigned* __restrict__ counter,
                                                float* __restrict__ out_scalar) {
    const float PR[NA] = {20.0f / 8.0f, 50.0f / 8.0f, 110.0f / 8.0f};   // ANCHORS/stride
    const float AR[NA] = {20.0f / IMGF, 50.0f / IMGF, 110.0f / IMGF};   // ANCHORS/IMAGE_SIZE

    int tid  = threadIdx.x;
    int base = blockIdx.x * (256 * NCPT) + tid;

    // ---- issue loads up front (lane-contiguous scalar loads) ----
    int bb[NCPT], rr[NCPT];
    float vt[NCPT][4];     // targets [c][plane]
    float vp[NCPT][12];    // x       [c][plane]
#pragma unroll
    for (int c = 0; c < NCPT; ++c) {
        int gc = base + c * 256;
        int b = gc / GG;
        int r = gc - b * GG;
        bb[c] = b; rr[c] = r;
        const float* tb = tg + (size_t)b * (4 * GG) + r;
#pragma unroll
        for (int p = 0; p < 4; ++p) vt[c][p] = tb[(size_t)p * GG];
        const float* xb = x + (size_t)b * (12 * GG) + r;
#pragma unroll
        for (int p = 0; p < 12; ++p) vp[c][p] = xb[(size_t)p * GG];
    }

    float l_fl = 0.0f, l_di = 0.0f;
    int   l_n  = 0;

#pragma unroll
    for (int c = 0; c < NCPT; ++c) {
        int b = bb[c], r = rr[c];
        int i = r / GDIM;
        int j = r - i * GDIM;
        float fi = (float)i, fj = (float)j;

        float tx  = vt[c][0];
        float ty  = vt[c][1];
        float trr = vt[c][2];
        float cf  = vt[c][3];
        float tgx = (fj + tx) * INV_G;
        float tgy = (fi + ty) * INV_G;

        // best anchor = argmax riou (first-max tie rule via strict >)
        int best = 0;
        float bestv = -1.0f;
#pragma unroll
        for (int a = 0; a < NA; ++a) {
            float q = fminf(trr, AR[a]) * rcp_(fmaxf(trr, AR[a]) + EPSF);
            float ri = q * q;
            if (ri > bestv) { bestv = ri; best = a; }
        }
        bool pos = (cf > 0.5f);

        size_t obase = (size_t)b * (NA * GG) + r;
        float sbx = 0.0f, sby = 0.0f, sbr = 0.0f;
#pragma unroll
        for (int a = 0; a < NA; ++a) {
            float p0 = vp[c][a * 4 + 0];
            float p1 = vp[c][a * 4 + 1];
            float p2 = vp[c][a * 4 + 2];
            float p3 = vp[c][a * 4 + 3];

            float sx = sigmoid_fast(p0);
            float sy = sigmoid_fast(p1);
            float br = PR[a] * __expf(p2) * INV_G;

            float e   = __expf(-p3);
            float pc  = rcp_(1.0f + e);
            float l1e = __logf(1.0f + e);     // = -log_sigmoid(p3)

            f32x4 o;
            o.x = (sx + fj) * 8.0f;
            o.y = (sy + fi) * 8.0f;
            o.z = br * IMGF;
            o.w = pc;
            __builtin_nontemporal_store(o, &out4[obase + (size_t)a * GG]);

            bool obj = pos && (a == best);
            float u = 1.0f - pc;
            l_fl += obj ? 0.25f * u * u * l1e : 0.75f * pc * pc * (p3 + l1e);

            if (a == best) { sbx = (sx + fj) * INV_G; sby = (sy + fi) * INV_G; sbr = br; }
        }

        if (pos) {
            l_n += 1;
            float dx = sbx - tgx, dy = sby - tgy;
            float d2 = dx * dx + dy * dy;
            float d  = sqrtf(d2 + EPSF);
            float r1 = sbr, r2 = trr;
            float rmin = fminf(r1, r2), rmax = fmaxf(r1, r2);
            float a1 = (d2 + r1 * r1 - r2 * r2) * rcp_(2.0f * d * r1 + EPSF);
            a1 = fminf(fmaxf(a1, -1.0f), 1.0f);
            float a2 = (d2 + r2 * r2 - r1 * r1) * rcp_(2.0f * d * r2 + EPSF);
            a2 = fminf(fmaxf(a2, -1.0f), 1.0f);
            float tt = (-d + r1 + r2) * (d + r1 - r2) * (d - r1 + r2) * (d + r1 + r2);
            tt = fmaxf(tt, 0.0f);
            float lens = r1 * r1 * acos_fast(a1) + r2 * r2 * acos_fast(a2) - 0.5f * sqrtf(tt);
            float inter = (d >= r1 + r2) ? 0.0f
                         : ((d <= rmax - rmin) ? PI_F * rmin * rmin : lens);
            float uni = PI_F * (r1 * r1 + r2 * r2) - inter;
            float iou = inter * rcp_(uni + EPSF);
            float s = d + r1 + r2;
            float pen = d2 * rcp_(s * s + EPSF);
            l_di += 1.0f - iou + pen;
        }
    }

    // wave64 reduce
    float l_nf = (float)l_n;
#pragma unroll
    for (int off = 32; off > 0; off >>= 1) {
        l_di += __shfl_down(l_di, off);
        l_fl += __shfl_down(l_fl, off);
        l_nf += __shfl_down(l_nf, off);
    }

    __shared__ float sdiou[4], sfl[4], snn[4];
    __shared__ int amlast;
    int wid  = tid >> 6;
    int lane = tid & 63;
    if (lane == 0) { sdiou[wid] = l_di; sfl[wid] = l_fl; snn[wid] = l_nf; }
    __syncthreads();
    if (tid == 0) {
        float ds = 0.0f, fs = 0.0f, ns = 0.0f;
#pragma unroll
        for (int w = 0; w < 4; ++w) { ds += sdiou[w]; fs += sfl[w]; ns += snn[w]; }
        // publish partials device-coherently (one dwordx4), then arrival counter
        f32x4 part; part.x = ds; part.y = fs; part.z = ns; part.w = 0.0f;
        asm volatile("global_store_dwordx4 %0, %1, off sc0 sc1\n\ts_waitcnt vmcnt(0)"
                     :: "v"(ws4 + blockIdx.x), "v"(part) : "memory");
        unsigned old = atomicAdd(counter, 1u);
        amlast = (old == NBLK - 1) ? 1 : 0;
    }
    __syncthreads();
    if (!amlast) return;

    // ---- last arriving block finalizes: 11 batched coherent dwordx4 loads ----
    const f32x4* p = ws4 + (size_t)tid * 11;     // max 2805+10 = 2815 < NSLOT
    f32x4 v0, v1, v2, v3, v4, v5, v6, v7, v8, v9, v10;
    asm volatile(
        "global_load_dwordx4 %0, %11, off sc0 sc1\n\t"
        "global_load_dwordx4 %1, %11, off offset:16 sc0 sc1\n\t"
        "global_load_dwordx4 %2, %11, off offset:32 sc0 sc1\n\t"
        "global_load_dwordx4 %3, %11, off offset:48 sc0 sc1\n\t"
        "global_load_dwordx4 %4, %11, off offset:64 sc0 sc1\n\t"
        "global_load_dwordx4 %5, %11, off offset:80 sc0 sc1\n\t"
        "global_load_dwordx4 %6, %11, off offset:96 sc0 sc1\n\t"
        "global_load_dwordx4 %7, %11, off offset:112 sc0 sc1\n\t"
        "global_load_dwordx4 %8, %11, off offset:128 sc0 sc1\n\t"
        "global_load_dwordx4 %9, %11, off offset:144 sc0 sc1\n\t"
        "global_load_dwordx4 %10, %11, off offset:160 sc0 sc1\n\t"
        "s_waitcnt vmcnt(0)"
        : "=&v"(v0), "=&v"(v1), "=&v"(v2), "=&v"(v3), "=&v"(v4), "=&v"(v5),
          "=&v"(v6), "=&v"(v7), "=&v"(v8), "=&v"(v9), "=&v"(v10)
        : "v"(p) : "memory");
    __builtin_amdgcn_sched_barrier(0);   // rule #18: keep uses below the waitcnt

    float ds = v0.x + v1.x + v2.x + v3.x + v4.x + v5.x + v6.x + v7.x + v8.x + v9.x + v10.x;
    float fs = v0.y + v1.y + v2.y + v3.y + v4.y + v5.y + v6.y + v7.y + v8.y + v9.y + v10.y;
    float ns = v0.z + v1.z + v2.z + v3.z + v4.z + v5.z + v6.z + v7.z + v8.z + v9.z + v10.z;

#pragma unroll
    for (int off = 32; off > 0; off >>= 1) {
        ds += __shfl_down(ds, off);
        fs += __shfl_down(fs, off);
        ns += __shfl_down(ns, off);
    }
    __syncthreads();   // safe reuse of shared arrays
    if (lane == 0) { sdiou[wid] = ds; sfl[wid] = fs; snn[wid] = ns; }
    __syncthreads();
    if (tid == 0) {
        float D = 0.0f, F = 0.0f, N = 0.0f;
#pragma unroll
        for (int w = 0; w < 4; ++w) { D += sdiou[w]; F += sfl[w]; N += snn[w]; }
        double n = (N < 1.0f) ? 1.0 : (double)N;
        out_scalar[0] = (float)((double)D / n + (double)F / (double)((size_t)NB * NA * GG));
    }
}

extern "C" void kernel_launch(void* const* d_in, const int* in_sizes, int n_in,
                              void* d_out, int out_size, void* d_ws, size_t ws_size,
                              hipStream_t stream) {
    const float* x  = (const float*)d_in[0];
    const float* tg = (const float*)d_in[1];
    float* out = (float*)d_out;
    f32x4* ws4 = (f32x4*)d_ws;
    unsigned* counter = (unsigned*)((char*)d_ws + (size_t)NSLOT * 16);

    // zero pad slots [NBLK, NSLOT) + counter, every launch (graph-safe)
    hipMemsetAsync((char*)d_ws + (size_t)NBLK * 16, 0,
                   (size_t)(NSLOT - NBLK) * 16 + sizeof(unsigned), stream);

    det_main<<<NBLK, 256, 0, stream>>>(x, tg, (f32x4*)out, ws4, counter,
                                       out + (size_t)NB * NA * GG * 4);
}

// Round 12
// 35.458 us; speedup vs baseline: 1.6427x; 1.5305x over previous
//
#include <hip/hip_runtime.h>

#define GDIM 104
#define GG (GDIM * GDIM)          // 10816
#define NA 3
#define NB 128
#define NBLK 1352                 // NB*GG / 1024 (1024 cells per block)
#define IMGF 832.0f
#define EPSF 1e-9f
#define PI_F 3.14159265358979323846f
#define INV_G (1.0f / 104.0f)

typedef float f32x4 __attribute__((ext_vector_type(4)));

// 1-instruction reciprocal (v_rcp_f32, rel err ~2^-22 — fine at threshold 348)
__device__ __forceinline__ float rcp_(float x) { return __builtin_amdgcn_rcpf(x); }

__device__ __forceinline__ float sigmoid_fast(float z) {
    return rcp_(1.0f + __expf(-z));
}

// acos minimax (Abramowitz-Stegun 4.4.45), |err| < 7e-5 rad
__device__ __forceinline__ float acos_fast(float x) {
    float ax = fabsf(x);
    float t = sqrtf(fmaxf(1.0f - ax, 0.0f));
    float p = fmaf(-0.0187293f, ax, 0.0742610f);
    p = fmaf(p, ax, -0.2121144f);
    p = fmaf(p, ax, 1.5707288f);
    float r = t * p;
    return (x < 0.0f) ? (PI_F - r) : r;
}

// async global->LDS, 16B per lane: lane l writes lds_base + l*16 from its own
// per-lane global address. Zero result-VGPRs -> the register allocator cannot
// serialize the batch; MLP lives in the vmcnt queue.
__device__ __forceinline__ void load_to_lds16(const float* g, float* l) {
    __builtin_amdgcn_global_load_lds(
        (const __attribute__((address_space(1))) void*)g,
        (__attribute__((address_space(3))) void*)l, 16, 0, 0);
}

// Block = 1024 cells. Wave w stages cells [w*256, w*256+256) of the block for
// all 16 planes (12 x + 4 targets) via 16 global_load_lds (1KB each). After
// vmcnt(0)+barrier, thread t computes cells {t + k*256} reading LDS at lane
// stride 4B (conflict-free), stores lane-contiguous float4 (ideal WRITE_SIZE).
__global__ __launch_bounds__(256) void det_main(const float* __restrict__ x,
                                                const float* __restrict__ tg,
                                                f32x4* __restrict__ out4,
                                                float* __restrict__ ws) {
    __shared__ float lds[16 * 1024];   // 64 KB

    const float PR[NA] = {20.0f / 8.0f, 50.0f / 8.0f, 110.0f / 8.0f};   // ANCHORS/stride
    const float AR[NA] = {20.0f / IMGF, 50.0f / IMGF, 110.0f / IMGF};   // ANCHORS/IMAGE_SIZE

    int tid  = threadIdx.x;
    int lane = tid & 63;
    int wid  = tid >> 6;

    // ---- staging: 16 global_load_lds per wave, all issued back-to-back ----
    {
        int chunk_gc = blockIdx.x * 1024 + wid * 256 + lane * 4;  // 4-cell chunk
        int cb = chunk_gc / GG;
        int cr = chunk_gc - cb * GG;          // chunk never crosses batch (GG%4==0)
        const float* xbase = x + (size_t)cb * (12 * GG) + cr;
        const float* tbase = tg + (size_t)cb * (4 * GG) + cr;
#pragma unroll
        for (int p = 0; p < 12; ++p)
            load_to_lds16(xbase + (size_t)p * GG, &lds[p * 1024 + wid * 256]);
#pragma unroll
        for (int p = 0; p < 4; ++p)
            load_to_lds16(tbase + (size_t)p * GG, &lds[(12 + p) * 1024 + wid * 256]);
    }
    asm volatile("s_waitcnt vmcnt(0)" ::: "memory");
    __syncthreads();

    float l_fl = 0.0f, l_di = 0.0f;
    int   l_n  = 0;

#pragma unroll
    for (int k = 0; k < 4; ++k) {
        int cell = tid + k * 256;
        int gc = blockIdx.x * 1024 + cell;
        int b = gc / GG;
        int r = gc - b * GG;
        int i = r / GDIM;
        int j = r - i * GDIM;
        float fi = (float)i, fj = (float)j;

        float tx  = lds[12 * 1024 + cell];
        float ty  = lds[13 * 1024 + cell];
        float trr = lds[14 * 1024 + cell];
        float cf  = lds[15 * 1024 + cell];
        float tgx = (fj + tx) * INV_G;
        float tgy = (fi + ty) * INV_G;

        // best anchor = argmax riou (first-max tie rule via strict >)
        int best = 0;
        float bestv = -1.0f;
#pragma unroll
        for (int a = 0; a < NA; ++a) {
            float q = fminf(trr, AR[a]) * rcp_(fmaxf(trr, AR[a]) + EPSF);
            float ri = q * q;
            if (ri > bestv) { bestv = ri; best = a; }
        }
        bool pos = (cf > 0.5f);

        size_t obase = (size_t)b * (NA * GG) + r;
        float sbx = 0.0f, sby = 0.0f, sbr = 0.0f;
#pragma unroll
        for (int a = 0; a < NA; ++a) {
            float p0 = lds[(a * 4 + 0) * 1024 + cell];
            float p1 = lds[(a * 4 + 1) * 1024 + cell];
            float p2 = lds[(a * 4 + 2) * 1024 + cell];
            float p3 = lds[(a * 4 + 3) * 1024 + cell];

            float sx = sigmoid_fast(p0);
            float sy = sigmoid_fast(p1);
            float br = PR[a] * __expf(p2) * INV_G;

            float e   = __expf(-p3);
            float pc  = rcp_(1.0f + e);
            float l1e = __logf(1.0f + e);     // = -log_sigmoid(p3)

            f32x4 o;
            o.x = (sx + fj) * 8.0f;
            o.y = (sy + fi) * 8.0f;
            o.z = br * IMGF;
            o.w = pc;
            __builtin_nontemporal_store(o, &out4[obase + (size_t)a * GG]);

            bool obj = pos && (a == best);
            float u = 1.0f - pc;
            l_fl += obj ? 0.25f * u * u * l1e : 0.75f * pc * pc * (p3 + l1e);

            if (a == best) { sbx = (sx + fj) * INV_G; sby = (sy + fi) * INV_G; sbr = br; }
        }

        if (pos) {
            l_n += 1;
            float dx = sbx - tgx, dy = sby - tgy;
            float d2 = dx * dx + dy * dy;
            float d  = sqrtf(d2 + EPSF);
            float r1 = sbr, r2 = trr;
            float rmin = fminf(r1, r2), rmax = fmaxf(r1, r2);
            float a1 = (d2 + r1 * r1 - r2 * r2) * rcp_(2.0f * d * r1 + EPSF);
            a1 = fminf(fmaxf(a1, -1.0f), 1.0f);
            float a2 = (d2 + r2 * r2 - r1 * r1) * rcp_(2.0f * d * r2 + EPSF);
            a2 = fminf(fmaxf(a2, -1.0f), 1.0f);
            float tt = (-d + r1 + r2) * (d + r1 - r2) * (d - r1 + r2) * (d + r1 + r2);
            tt = fmaxf(tt, 0.0f);
            float lens = r1 * r1 * acos_fast(a1) + r2 * r2 * acos_fast(a2) - 0.5f * sqrtf(tt);
            float inter = (d >= r1 + r2) ? 0.0f
                         : ((d <= rmax - rmin) ? PI_F * rmin * rmin : lens);
            float uni = PI_F * (r1 * r1 + r2 * r2) - inter;
            float iou = inter * rcp_(uni + EPSF);
            float s = d + r1 + r2;
            float pen = d2 * rcp_(s * s + EPSF);
            l_di += 1.0f - iou + pen;
        }
    }

    // wave64 reduce
    float l_nf = (float)l_n;
#pragma unroll
    for (int off = 32; off > 0; off >>= 1) {
        l_di += __shfl_down(l_di, off);
        l_fl += __shfl_down(l_fl, off);
        l_nf += __shfl_down(l_nf, off);
    }

    __shared__ float sdiou[4], sfl[4], snn[4];
    if (lane == 0) { sdiou[wid] = l_di; sfl[wid] = l_fl; snn[wid] = l_nf; }
    __syncthreads();
    if (tid == 0) {
        float ds = 0.0f, fs = 0.0f, ns = 0.0f;
#pragma unroll
        for (int w = 0; w < 4; ++w) { ds += sdiou[w]; fs += sfl[w]; ns += snn[w]; }
        ws[blockIdx.x]            = ds;
        ws[NBLK + blockIdx.x]     = fs;
        ws[2 * NBLK + blockIdx.x] = ns;
    }
}

__global__ __launch_bounds__(256) void det_finalize(const float* __restrict__ ws,
                                                    float* __restrict__ out_scalar) {
    float ds = 0.0f, fs = 0.0f, ns = 0.0f;
    for (int k = threadIdx.x; k < NBLK; k += 256) {
        ds += ws[k];
        fs += ws[NBLK + k];
        ns += ws[2 * NBLK + k];
    }
#pragma unroll
    for (int off = 32; off > 0; off >>= 1) {
        ds += __shfl_down(ds, off);
        fs += __shfl_down(fs, off);
        ns += __shfl_down(ns, off);
    }
    __shared__ float s0[4], s1[4], s2[4];
    int wid  = threadIdx.x >> 6;
    int lane = threadIdx.x & 63;
    if (lane == 0) { s0[wid] = ds; s1[wid] = fs; s2[wid] = ns; }
    __syncthreads();
    if (threadIdx.x == 0) {
        float D = 0.0f, F = 0.0f, N = 0.0f;
#pragma unroll
        for (int w = 0; w < 4; ++w) { D += s0[w]; F += s1[w]; N += s2[w]; }
        double n = (N < 1.0f) ? 1.0 : (double)N;
        out_scalar[0] = (float)((double)D / n + (double)F / (double)((size_t)NB * NA * GG));
    }
}

extern "C" void kernel_launch(void* const* d_in, const int* in_sizes, int n_in,
                              void* d_out, int out_size, void* d_ws, size_t ws_size,
                              hipStream_t stream) {
    const float* x  = (const float*)d_in[0];
    const float* tg = (const float*)d_in[1];
    float* out = (float*)d_out;
    float* ws  = (float*)d_ws;

    det_main<<<NBLK, 256, 0, stream>>>(x, tg, (f32x4*)out, ws);
    det_finalize<<<1, 256, 0, stream>>>(ws, out + (size_t)NB * NA * GG * 4);
}

// Round 13
// 34.089 us; speedup vs baseline: 1.7087x; 1.0402x over previous
//
#include <hip/hip_runtime.h>

#define GDIM 104
#define GG (GDIM * GDIM)          // 10816
#define NA 3
#define NB 128
#define TILE 512                  // cells per tile
#define NT_TOTAL 2704             // NB*GG / TILE
#define NBLOCKS 512               // 2 per CU, all resident
#define IMGF 832.0f
#define EPSF 1e-9f
#define PI_F 3.14159265358979323846f
#define INV_G (1.0f / 104.0f)

typedef float f32x4 __attribute__((ext_vector_type(4)));

__device__ __forceinline__ float rcp_(float x) { return __builtin_amdgcn_rcpf(x); }

__device__ __forceinline__ float sigmoid_fast(float z) {
    return rcp_(1.0f + __expf(-z));
}

// acos minimax (Abramowitz-Stegun 4.4.45), |err| < 7e-5 rad
__device__ __forceinline__ float acos_fast(float x) {
    float ax = fabsf(x);
    float t = sqrtf(fmaxf(1.0f - ax, 0.0f));
    float p = fmaf(-0.0187293f, ax, 0.0742610f);
    p = fmaf(p, ax, -0.2121144f);
    p = fmaf(p, ax, 1.5707288f);
    float r = t * p;
    return (x < 0.0f) ? (PI_F - r) : r;
}

__device__ __forceinline__ void load_to_lds16(const float* g, float* l) {
    __builtin_amdgcn_global_load_lds(
        (const __attribute__((address_space(1))) void*)g,
        (__attribute__((address_space(3))) void*)l, 16, 0, 0);
}

// Double-buffered DMA pipeline: 512 persistent blocks, each grid-strides over
// 512-cell tiles. stage(t+1) overlaps compute(t); counted vmcnt(6) (= prev
// compute's 6 output stores) instead of a full drain; raw s_barrier so the
// compiler can't insert vmcnt(0).
__global__ __launch_bounds__(256) void det_main(const float* __restrict__ x,
                                                const float* __restrict__ tg,
                                                f32x4* __restrict__ out4,
                                                float* __restrict__ ws) {
    __shared__ float lds[2][16][TILE];   // 64 KB

    const float PR[NA] = {20.0f / 8.0f, 50.0f / 8.0f, 110.0f / 8.0f};   // ANCHORS/stride
    const float AR[NA] = {20.0f / IMGF, 50.0f / IMGF, 110.0f / IMGF};   // ANCHORS/IMAGE_SIZE

    int tid  = threadIdx.x;
    int lane = tid & 63;
    int wid  = tid >> 6;
    int bid  = blockIdx.x;

    // wave w stages planes [4w, 4w+4): waves 0-2 -> x planes 0..11, wave 3 -> targets
    auto STAGE = [&](int T, int buf) {
#pragma unroll
        for (int q = 0; q < 4; ++q) {
            int p = 4 * wid + q;
#pragma unroll
            for (int h = 0; h < 2; ++h) {
                int gc = T * TILE + h * 256 + lane * 4;   // 4-cell chunk, GG%4==0
                int cb = gc / GG;
                int cr = gc - cb * GG;
                const float* src = (p < 12)
                    ? x  + (size_t)cb * (12 * GG) + (size_t)p * GG + cr
                    : tg + (size_t)cb * (4 * GG) + (size_t)(p - 12) * GG + cr;
                load_to_lds16(src, &lds[buf][p][h * 256]);
            }
        }
    };

    float l_fl = 0.0f, l_di = 0.0f;
    int   l_n  = 0;

    int NTb = (NT_TOTAL - bid + NBLOCKS - 1) / NBLOCKS;   // 5 or 6 tiles

    STAGE(bid, 0);

    for (int m = 0; m < NTb; ++m) {
        int T = bid + m * NBLOCKS;
        int buf = m & 1;

        if (m == 0) { asm volatile("s_waitcnt vmcnt(0)" ::: "memory"); }
        else        { asm volatile("s_waitcnt vmcnt(6)" ::: "memory"); }
        __builtin_amdgcn_s_barrier();          // all waves' stage(T) landed
        __builtin_amdgcn_sched_barrier(0);

        if (m + 1 < NTb) STAGE(bid + (m + 1) * NBLOCKS, buf ^ 1);  // overlap w/ compute

#pragma unroll
        for (int k = 0; k < 2; ++k) {
            int cell = k * 256 + tid;
            int gc = T * TILE + cell;
            int b = gc / GG;
            int r = gc - b * GG;
            int i = r / GDIM;
            int j = r - i * GDIM;
            float fi = (float)i, fj = (float)j;

            float tx  = lds[buf][12][cell];
            float ty  = lds[buf][13][cell];
            float trr = lds[buf][14][cell];
            float cf  = lds[buf][15][cell];
            float tgx = (fj + tx) * INV_G;
            float tgy = (fi + ty) * INV_G;

            // best anchor = argmax riou (first-max tie rule via strict >)
            int best = 0;
            float bestv = -1.0f;
#pragma unroll
            for (int a = 0; a < NA; ++a) {
                float q = fminf(trr, AR[a]) * rcp_(fmaxf(trr, AR[a]) + EPSF);
                float ri = q * q;
                if (ri > bestv) { bestv = ri; best = a; }
            }
            bool pos = (cf > 0.5f);

            size_t obase = (size_t)b * (NA * GG) + r;
            float sbx = 0.0f, sby = 0.0f, sbr = 0.0f;
#pragma unroll
            for (int a = 0; a < NA; ++a) {
                float p0 = lds[buf][a * 4 + 0][cell];
                float p1 = lds[buf][a * 4 + 1][cell];
                float p2 = lds[buf][a * 4 + 2][cell];
                float p3 = lds[buf][a * 4 + 3][cell];

                float sx = sigmoid_fast(p0);
                float sy = sigmoid_fast(p1);
                float br = PR[a] * __expf(p2) * INV_G;

                float e   = __expf(-p3);
                float pc  = rcp_(1.0f + e);
                float l1e = __logf(1.0f + e);     // = -log_sigmoid(p3)

                f32x4 o;
                o.x = (sx + fj) * 8.0f;
                o.y = (sy + fi) * 8.0f;
                o.z = br * IMGF;
                o.w = pc;
                __builtin_nontemporal_store(o, &out4[obase + (size_t)a * GG]);

                bool obj = pos && (a == best);
                float u = 1.0f - pc;
                l_fl += obj ? 0.25f * u * u * l1e : 0.75f * pc * pc * (p3 + l1e);

                if (a == best) { sbx = (sx + fj) * INV_G; sby = (sy + fi) * INV_G; sbr = br; }
            }

            if (pos) {
                l_n += 1;
                float dx = sbx - tgx, dy = sby - tgy;
                float d2 = dx * dx + dy * dy;
                float d  = sqrtf(d2 + EPSF);
                float r1 = sbr, r2 = trr;
                float rmin = fminf(r1, r2), rmax = fmaxf(r1, r2);
                float a1 = (d2 + r1 * r1 - r2 * r2) * rcp_(2.0f * d * r1 + EPSF);
                a1 = fminf(fmaxf(a1, -1.0f), 1.0f);
                float a2 = (d2 + r2 * r2 - r1 * r1) * rcp_(2.0f * d * r2 + EPSF);
                a2 = fminf(fmaxf(a2, -1.0f), 1.0f);
                float tt = (-d + r1 + r2) * (d + r1 - r2) * (d - r1 + r2) * (d + r1 + r2);
                tt = fmaxf(tt, 0.0f);
                float lens = r1 * r1 * acos_fast(a1) + r2 * r2 * acos_fast(a2) - 0.5f * sqrtf(tt);
                float inter = (d >= r1 + r2) ? 0.0f
                             : ((d <= rmax - rmin) ? PI_F * rmin * rmin : lens);
                float uni = PI_F * (r1 * r1 + r2 * r2) - inter;
                float iou = inter * rcp_(uni + EPSF);
                float s = d + r1 + r2;
                float pen = d2 * rcp_(s * s + EPSF);
                l_di += 1.0f - iou + pen;
            }
        }

        __builtin_amdgcn_s_barrier();          // LDS reads done before next overwrite
        __builtin_amdgcn_sched_barrier(0);
    }

    // wave64 reduce
    float l_nf = (float)l_n;
#pragma unroll
    for (int off = 32; off > 0; off >>= 1) {
        l_di += __shfl_down(l_di, off);
        l_fl += __shfl_down(l_fl, off);
        l_nf += __shfl_down(l_nf, off);
    }

    __shared__ float sdiou[4], sfl[4], snn[4];
    if (lane == 0) { sdiou[wid] = l_di; sfl[wid] = l_fl; snn[wid] = l_nf; }
    __syncthreads();
    if (tid == 0) {
        float ds = 0.0f, fs = 0.0f, ns = 0.0f;
#pragma unroll
        for (int w = 0; w < 4; ++w) { ds += sdiou[w]; fs += sfl[w]; ns += snn[w]; }
        ws[bid]               = ds;
        ws[NBLOCKS + bid]     = fs;
        ws[2 * NBLOCKS + bid] = ns;
    }
}

__global__ __launch_bounds__(256) void det_finalize(const float* __restrict__ ws,
                                                    float* __restrict__ out_scalar) {
    float ds = 0.0f, fs = 0.0f, ns = 0.0f;
    for (int k = threadIdx.x; k < NBLOCKS; k += 256) {
        ds += ws[k];
        fs += ws[NBLOCKS + k];
        ns += ws[2 * NBLOCKS + k];
    }
#pragma unroll
    for (int off = 32; off > 0; off >>= 1) {
        ds += __shfl_down(ds, off);
        fs += __shfl_down(fs, off);
        ns += __shfl_down(ns, off);
    }
    __shared__ float s0[4], s1[4], s2[4];
    int wid  = threadIdx.x >> 6;
    int lane = threadIdx.x & 63;
    if (lane == 0) { s0[wid] = ds; s1[wid] = fs; s2[wid] = ns; }
    __syncthreads();
    if (threadIdx.x == 0) {
        float D = 0.0f, F = 0.0f, N = 0.0f;
#pragma unroll
        for (int w = 0; w < 4; ++w) { D += s0[w]; F += s1[w]; N += s2[w]; }
        double n = (N < 1.0f) ? 1.0 : (double)N;
        out_scalar[0] = (float)((double)D / n + (double)F / (double)((size_t)NB * NA * GG));
    }
}

extern "C" void kernel_launch(void* const* d_in, const int* in_sizes, int n_in,
                              void* d_out, int out_size, void* d_ws, size_t ws_size,
                              hipStream_t stream) {
    const float* x  = (const float*)d_in[0];
    const float* tg = (const float*)d_in[1];
    float* out = (float*)d_out;
    float* ws  = (float*)d_ws;

    det_main<<<NBLOCKS, 256, 0, stream>>>(x, tg, (f32x4*)out, ws);
    det_finalize<<<1, 256, 0, stream>>>(ws, out + (size_t)NB * NA * GG * 4);
}